// Round 2
// baseline (94.114 us; speedup 1.0000x reference)
//
#include <hip/hip_runtime.h>
#include <math.h>

// Problem constants (B=2, N=512, E=128, H=8, D=16)
#define BATCH 2
#define NSEQ  512
#define EDIM  128
#define HNUM  8
#define DDIM  16
#define MROWS (BATCH*NSEQ)   // 1024

// ---------------------------------------------------------------------------
// QKV GEMM: qkv[1024,384] = x[1024,128] @ w_qkv[384,128]^T
// Tile 32x64, 256 threads, micro-tile 2x4. LDS stored as float4 [r][k4] with
// XOR swizzle k4 ^ ((r>>2)&7) (unpadded, 16B aligned) -> <=2-way bank alias
// on both the strided B-frag reads and the broadcast A-frag reads.
// ---------------------------------------------------------------------------
__global__ __launch_bounds__(256)
void qkv_gemm(const float* __restrict__ x, const float* __restrict__ w,
              float* __restrict__ qkv) {
    __shared__ float4 As[32 * 32];   // [r][k4'] : 16 KB
    __shared__ float4 Bs[64 * 32];   // [r][k4'] : 32 KB

    const int tid  = threadIdx.x;
    const int row0 = blockIdx.y * 32;
    const int col0 = blockIdx.x * 64;

    #pragma unroll
    for (int it = 0; it < 4; ++it) {                  // A: 32 rows x 32 float4
        int idx = tid + it * 256;
        int r = idx >> 5, k4 = idx & 31;
        As[r * 32 + (k4 ^ ((r >> 2) & 7))] =
            ((const float4*)(x + (size_t)(row0 + r) * 128))[k4];
    }
    #pragma unroll
    for (int it = 0; it < 8; ++it) {                  // B: 64 rows x 32 float4
        int idx = tid + it * 256;
        int r = idx >> 5, k4 = idx & 31;
        Bs[r * 32 + (k4 ^ ((r >> 2) & 7))] =
            ((const float4*)(w + (size_t)(col0 + r) * 128))[k4];
    }
    __syncthreads();

    const int ty = tid >> 4;          // 0..15 -> rows ty*2, ty*2+1
    const int tx = tid & 15;          // 0..15 -> cols tx*4..tx*4+3
    const int ra  = ty * 2;
    const int swa = (ra >> 2) & 7;    // same for ra and ra+1 (ra even)
    const int rb  = tx * 4;
    const int swb = tx & 7;           // (rb>>2)&7 == tx&7

    float acc[2][4] = {};
    #pragma unroll
    for (int k4 = 0; k4 < 32; ++k4) {
        float4 a0 = As[ ra      * 32 + (k4 ^ swa)];
        float4 a1 = As[(ra + 1) * 32 + (k4 ^ swa)];
        float4 bv[4];
        #pragma unroll
        for (int j = 0; j < 4; ++j)
            bv[j] = Bs[(rb + j) * 32 + (k4 ^ swb)];
        #pragma unroll
        for (int j = 0; j < 4; ++j) {
            acc[0][j] = fmaf(a0.x, bv[j].x, acc[0][j]);
            acc[0][j] = fmaf(a0.y, bv[j].y, acc[0][j]);
            acc[0][j] = fmaf(a0.z, bv[j].z, acc[0][j]);
            acc[0][j] = fmaf(a0.w, bv[j].w, acc[0][j]);
            acc[1][j] = fmaf(a1.x, bv[j].x, acc[1][j]);
            acc[1][j] = fmaf(a1.y, bv[j].y, acc[1][j]);
            acc[1][j] = fmaf(a1.z, bv[j].z, acc[1][j]);
            acc[1][j] = fmaf(a1.w, bv[j].w, acc[1][j]);
        }
    }

    #pragma unroll
    for (int i = 0; i < 2; ++i) {
        float* crow = qkv + (size_t)(row0 + ra + i) * 384 + col0 + rb;
        *(float4*)crow = make_float4(acc[i][0], acc[i][1], acc[i][2], acc[i][3]);
    }
}

// ---------------------------------------------------------------------------
// Fused attention + output projection. One block (512 thr = 8 waves) per
// (b,n) row; wave h handles head h. Uses the exact identity
//   lrelu(t) = 0.505*t + 0.495*|t|
// so the linear part folds into per-head precomputed constants and the inner
// loop is 2 VALU ops per (m,d): t = fma(s,w,b); dot = fma(c, |t|, dot).
// ---------------------------------------------------------------------------
__global__ __launch_bounds__(512)
void attn_proj(const float* __restrict__ qkv, const float* __restrict__ e,
               const float* __restrict__ wekv, const float* __restrict__ bekv,
               const float* __restrict__ wprj, const float* __restrict__ bprj,
               float* __restrict__ out) {
    __shared__ float hat_s[EDIM];

    const int tid  = threadIdx.x;
    const int lane = tid & 63;
    const int h    = tid >> 6;                 // wave id == head
    const int bn   = blockIdx.x;               // b*N + n

    const float* qrow = qkv + (size_t)bn * 384 + h * DDIM;
    const float* krow = qrow + EDIM;
    const float* vrow = qrow + 2 * EDIM;
    const float* erow = e + (size_t)bn * NSEQ;

    const float SC = 0.25f * 1.44269504088896340736f;  // 1/sqrt(D) * log2(e)

    // ---- per-head precompute (pass-1 constants) ----
    float wk[DDIM], bk[DDIM], cd[DDIM];
    float qk = 0.f, qwk = 0.f, qbk = 0.f;
    #pragma unroll
    for (int d = 0; d < DDIM; ++d) {
        float q = qrow[d];
        qk  = fmaf(q, krow[d], qk);
        wk[d] = wekv[h * DDIM + d];
        bk[d] = bekv[h * DDIM + d];
        qwk = fmaf(q, wk[d], qwk);
        qbk = fmaf(q, bk[d], qbk);
        cd[d] = 0.495f * SC * q;
    }
    const float Alin = SC * 0.505f * qwk;
    const float base = SC * (qk + 0.505f * qbk);

    // ---- pass 1: dots (log2 domain) + max ----
    float dots[NSEQ / 64], ev[NSEQ / 64];
    float lmax = -1e30f;
    #pragma unroll
    for (int c = 0; c < NSEQ / 64; ++c) {
        float s = erow[c * 64 + lane];
        ev[c] = s;
        float dot = fmaf(s, Alin, base);
        #pragma unroll
        for (int d = 0; d < DDIM; ++d) {
            float t = fmaf(s, wk[d], bk[d]);
            dot = fmaf(cd[d], fabsf(t), dot);   // |t| is a free VOP3 modifier
        }
        dots[c] = dot;
        lmax = fmaxf(lmax, dot);
    }
    #pragma unroll
    for (int off = 32; off >= 1; off >>= 1)
        lmax = fmaxf(lmax, __shfl_xor(lmax, off, 64));

    // ---- pass 2: p = exp2(dot-max); sums ----
    float wvv[DDIM], bv[DDIM], racc[DDIM];
    #pragma unroll
    for (int d = 0; d < DDIM; ++d) {
        wvv[d]  = wekv[EDIM + h * DDIM + d];
        bv[d]   = bekv[EDIM + h * DDIM + d];
        racc[d] = 0.f;
    }
    float sp = 0.f, spe = 0.f;
    #pragma unroll
    for (int c = 0; c < NSEQ / 64; ++c) {
        float p = __builtin_amdgcn_exp2f(dots[c] - lmax);
        float s = ev[c];
        sp  += p;
        spe  = fmaf(p, s, spe);
        float pm = 0.495f * p;
        #pragma unroll
        for (int d = 0; d < DDIM; ++d) {
            float t = fmaf(s, wvv[d], bv[d]);
            racc[d] = fmaf(pm, fabsf(t), racc[d]);
        }
    }

    // ---- butterfly reduce sp, spe, racc[16] across the wave ----
    #pragma unroll
    for (int off = 1; off < 64; off <<= 1) {
        sp  += __shfl_xor(sp,  off, 64);
        spe += __shfl_xor(spe, off, 64);
        #pragma unroll
        for (int d = 0; d < DDIM; ++d)
            racc[d] += __shfl_xor(racc[d], off, 64);
    }

    // lane d selects racc[d]; combine with analytic linear part
    float rsel = racc[0];
    #pragma unroll
    for (int d = 1; d < DDIM; ++d) rsel = (lane == d) ? racc[d] : rsel;
    if (lane < DDIM) {
        float wvs = wekv[EDIM + h * DDIM + lane];
        float bvs = bekv[EDIM + h * DDIM + lane];
        float acc = rsel + 0.505f * (fmaf(wvs, spe, bvs * sp));
        hat_s[h * DDIM + lane] = vrow[lane] + acc / sp;
    }
    __syncthreads();

    // ---- output projection: out[c] = b[c] + sum_k hat[k]*wprj[c,k] ----
    const int c    = tid >> 2;       // 0..127
    const int quad = tid & 3;        // 32-k slice
    const float4* wp = (const float4*)(wprj + (size_t)c * EDIM + quad * 32);
    const float4* hp = (const float4*)(hat_s + quad * 32);
    float s = 0.f;
    #pragma unroll
    for (int j = 0; j < 8; ++j) {
        float4 wv4 = wp[j], hv4 = hp[j];
        s = fmaf(wv4.x, hv4.x, s);
        s = fmaf(wv4.y, hv4.y, s);
        s = fmaf(wv4.z, hv4.z, s);
        s = fmaf(wv4.w, hv4.w, s);
    }
    s += __shfl_xor(s, 1, 64);
    s += __shfl_xor(s, 2, 64);
    if (quad == 0)
        out[(size_t)bn * EDIM + c] = s + bprj[c];
}

// ---------------------------------------------------------------------------
extern "C" void kernel_launch(void* const* d_in, const int* in_sizes, int n_in,
                              void* d_out, int out_size, void* d_ws, size_t ws_size,
                              hipStream_t stream) {
    const float* x     = (const float*)d_in[0];  // [B,N,128]
    const float* e     = (const float*)d_in[1];  // [B,N,N]
    const float* w_qkv = (const float*)d_in[2];  // [384,128]
    const float* w_ekv = (const float*)d_in[3];  // [256,1]
    const float* b_ekv = (const float*)d_in[4];  // [256]
    const float* w_prj = (const float*)d_in[5];  // [128,128]
    const float* b_prj = (const float*)d_in[6];  // [128]
    float* out = (float*)d_out;

    float* qkv = (float*)d_ws;                   // [1024, 384]

    qkv_gemm<<<dim3(384 / 64, MROWS / 32), 256, 0, stream>>>(x, w_qkv, qkv);

    attn_proj<<<MROWS, 512, 0, stream>>>(qkv, e, w_ekv, b_ekv, w_prj, b_prj, out);
}